// Round 4
// baseline (418.560 us; speedup 1.0000x reference)
//
#include <hip/hip_runtime.h>

#define D_MODEL 2048
#define T_SEQ   2048
#define NBATCH  2
#define NH      16
#define NG      4
#define HD      128
#define NQKV    3072   // 2048 Q + 512 K + 512 V

typedef short bf16x8 __attribute__((ext_vector_type(8)));
typedef float f32x4  __attribute__((ext_vector_type(4)));
typedef short s16x4  __attribute__((ext_vector_type(4)));

__device__ __forceinline__ short f2bf(float f) {
  union { float f; unsigned u; } v; v.f = f;
  unsigned r = v.u + 0x7fffu + ((v.u >> 16) & 1u);   // RNE
  return (short)(r >> 16);
}

__device__ __forceinline__ float bf2f(short s) {
  union { unsigned u; float f; } v; v.u = ((unsigned)(unsigned short)s) << 16;
  return v.f;
}

__device__ __forceinline__ float fast_exp2(float x) {
#if __has_builtin(__builtin_amdgcn_exp2f)
  return __builtin_amdgcn_exp2f(x);
#else
  return __expf(x * 0.6931471805599453f);
#endif
}

__device__ __forceinline__ void gload16(const void* g, void* l) {
  __builtin_amdgcn_global_load_lds(
      (const __attribute__((address_space(1))) void*)g,
      (__attribute__((address_space(3))) void*)l, 16, 0, 0);
}

// ---------------- convert x (fp32 -> bf16) ----------------
__global__ __launch_bounds__(256) void convert_x_kernel(
    const float* __restrict__ x, short* __restrict__ o, int n) {
  int i = (blockIdx.x * 256 + threadIdx.x) * 4;
  if (i >= n) return;
  float4 v = *(const float4*)(x + i);
  s16x4 s;
  s[0] = f2bf(v.x); s[1] = f2bf(v.y); s[2] = f2bf(v.z); s[3] = f2bf(v.w);
  *(s16x4*)(o + i) = s;
}

// ------------- transpose+convert weights: dst[n][k] = W[k][n] -------------
__global__ __launch_bounds__(256) void wtrans_kernel(
    const float* __restrict__ W, short* __restrict__ dst,
    int K, int N, int rowOff, int dstStride) {
  __shared__ float t[32][33];
  int tx = threadIdx.x & 31, ty = threadIdx.x >> 5;   // ty 0..7
  int kb = blockIdx.x * 32, nb = blockIdx.y * 32;
#pragma unroll
  for (int i = 0; i < 4; ++i)
    t[ty + 8*i][tx] = W[(long)(kb + ty + 8*i) * N + nb + tx];
  __syncthreads();
#pragma unroll
  for (int i = 0; i < 4; ++i)
    dst[(long)(rowOff + nb + ty + 8*i) * dstStride + kb + tx] = f2bf(t[tx][ty + 8*i]);
}

// ------------- transpose V slice of QKV -> VT[b][g][d][s] (bf16) -------------
__global__ __launch_bounds__(256) void vtrans_kernel(
    const short* __restrict__ qkv, short* __restrict__ vt) {
  __shared__ short t[32][33];
  int bg = blockIdx.z; int b = bg >> 2, g = bg & 3;
  int sb = blockIdx.x * 32, db = blockIdx.y * 32;
  int tx = threadIdx.x & 31, ty = threadIdx.x >> 5;
  const short* src = qkv + (long)(b * T_SEQ) * NQKV + D_MODEL + NG * HD + g * HD;
#pragma unroll
  for (int i = 0; i < 4; ++i)
    t[ty + 8*i][tx] = src[(long)(sb + ty + 8*i) * NQKV + db + tx];
  __syncthreads();
  short* dst = vt + ((long)bg * HD + db) * T_SEQ + sb;
#pragma unroll
  for (int i = 0; i < 4; ++i)
    dst[(long)(ty + 8*i) * T_SEQ + tx] = t[tx][ty + 8*i];
}

// ---------------- bf16 MFMA GEMM: C[M][N] = A[M][K] @ BT[N][K]^T + bias ----------------
__global__ __launch_bounds__(256) void gemm_kernel(
    const short* __restrict__ A, const short* __restrict__ BT,
    const float* __restrict__ b0, const float* __restrict__ b1, const float* __restrict__ b2,
    void* __restrict__ Cout, int M, int N, int K, int mode) {
  __shared__ __align__(16) short As[128 * 32];
  __shared__ __align__(16) short Bs[128 * 32];
  const int tid = threadIdx.x;
  const int w = tid >> 6, lane = tid & 63;
  const int l15 = lane & 15, quad = lane >> 4;
  const int wr = w & 1, wc = w >> 1;
  const int nb = blockIdx.x, mb = blockIdx.y;
  const short* Ab = A + (long)mb * 128 * K;
  const short* Bb = BT + (long)nb * 128 * K;

  f32x4 acc[4][4];
#pragma unroll
  for (int i = 0; i < 4; ++i)
#pragma unroll
    for (int j = 0; j < 4; ++j) acc[i][j] = 0.0f;

  for (int k0 = 0; k0 < K; k0 += 32) {
    __syncthreads();
#pragma unroll
    for (int t = 0; t < 2; ++t) {
      int chunk = w * 128 + t * 64 + lane;
      int r = chunk >> 2, c = chunk & 3;
      int gc = c ^ ((r >> 1) & 3);              // XOR swizzle (16B chunks)
      gload16(Ab + (long)r * K + k0 + gc * 8, As + (w * 128 + t * 64) * 8);
      gload16(Bb + (long)r * K + k0 + gc * 8, Bs + (w * 128 + t * 64) * 8);
    }
    __syncthreads();
    bf16x8 af[4], bfr[4];
#pragma unroll
    for (int i = 0; i < 4; ++i) {
      int r = wr * 64 + i * 16 + l15;
      af[i] = *(const bf16x8*)(As + r * 32 + ((quad ^ ((r >> 1) & 3)) * 8));
    }
#pragma unroll
    for (int j = 0; j < 4; ++j) {
      int r = wc * 64 + j * 16 + l15;
      bfr[j] = *(const bf16x8*)(Bs + r * 32 + ((quad ^ ((r >> 1) & 3)) * 8));
    }
#pragma unroll
    for (int i = 0; i < 4; ++i)
#pragma unroll
      for (int j = 0; j < 4; ++j)
        acc[i][j] = __builtin_amdgcn_mfma_f32_16x16x32_bf16(af[i], bfr[j], acc[i][j], 0, 0, 0);
  }

  float biasv[4];
#pragma unroll
  for (int j = 0; j < 4; ++j) {
    int col = nb * 128 + wc * 64 + j * 16 + l15;
    float bv;
    if (mode == 0) {
      if (col < 2048)      bv = b0[col];
      else if (col < 2560) bv = b1[col - 2048];
      else                 bv = b2[col - 2560];
    } else bv = b0[col];
    biasv[j] = bv;
  }
  if (mode == 0) {
    short* C = (short*)Cout;
#pragma unroll
    for (int i = 0; i < 4; ++i)
#pragma unroll
      for (int j = 0; j < 4; ++j)
#pragma unroll
        for (int r = 0; r < 4; ++r) {
          int row = mb * 128 + wr * 64 + i * 16 + quad * 4 + r;
          int col = nb * 128 + wc * 64 + j * 16 + l15;
          C[(long)row * N + col] = f2bf(acc[i][j][r] + biasv[j]);
        }
  } else {
    float* C = (float*)Cout;
#pragma unroll
    for (int i = 0; i < 4; ++i)
#pragma unroll
      for (int j = 0; j < 4; ++j)
#pragma unroll
        for (int r = 0; r < 4; ++r) {
          int row = mb * 128 + wr * 64 + i * 16 + quad * 4 + r;
          int col = nb * 128 + wc * 64 + j * 16 + l15;
          C[(long)row * N + col] = acc[i][j][r] + biasv[j];
        }
  }
}

// ---------------- fused attention v4: v2 skeleton + M-split=2 ----------------
// grid: (T/128, NH, B); block 256 (4 waves). 128 Q rows per block; each wave
// owns 32 Q rows as TWO 16-row A-fragment sets in registers. Per 64-col
// s-tile iter: QK (sets sequential, sacc = 1 set of 4 f32x4), exp->Ps
// (same-wave rows only, no barrier), PV with V-fragment reads SHARED across
// both sets. 2 barriers + one K/V staging serve 128 Q rows (v2: 64).
// LDS: Ks 16K + Vs 16K + Ps 16K = 48KB -> 3 blocks/CU. Q staged through
// Ks+Vs (32KB) once at start. All swizzles identical to v2 (0 conflicts).
__global__ __launch_bounds__(256, 3) void attn_kernel(
    const short* __restrict__ qkv, const short* __restrict__ vt,
    short* __restrict__ aout) {
  __shared__ __align__(16) short smem[24576];   // 48 KB
  short* Ks = smem;              // 64 rows(s) x 128 (k)
  short* Vs = smem + 8192;       // 128 rows(d) x 64 (s)
  short* Ps = smem + 16384;      // 128 rows(q) x 64 (s)

  const int tid = threadIdx.x;
  const int w = tid >> 6, lane = tid & 63;
  const int l15 = lane & 15, quad = lane >> 4;
  const int qt = blockIdx.x, h = blockIdx.y, b = blockIdx.z;
  const int g = h >> 2;
  const short* qbase = qkv + (long)(b * T_SEQ + qt * 128) * NQKV + h * HD;
  const short* kbase = qkv + (long)(b * T_SEQ) * NQKV + D_MODEL + g * HD;
  const short* vbase = vt + (long)(b * NG + g) * HD * T_SEQ;
  const float QSCALE = 0.08838834764831845f * 1.4426950408889634f;  // 1/sqrt(128)*log2(e)

  // ---- stage Q tile (128x128) through Ks+Vs, pull A-fragments to regs ----
#pragma unroll
  for (int t = 0; t < 8; ++t) {
    int chunk = w * 512 + t * 64 + lane;        // 0..2047
    int r = chunk >> 4, c = chunk & 15;
    int gc = c ^ (r & 15);
    gload16(qbase + (long)r * NQKV + gc * 8, smem + (w * 512 + t * 64) * 8);
  }
  __syncthreads();
  bf16x8 qfrag[2][4];
#pragma unroll
  for (int set = 0; set < 2; ++set) {
    int qr = w * 32 + set * 16 + l15;
#pragma unroll
    for (int ks = 0; ks < 4; ++ks) {
      bf16x8 v = *(const bf16x8*)(smem + qr * 128 + (((ks * 4 + quad) ^ (qr & 15)) * 8));
#pragma unroll
      for (int e = 0; e < 8; ++e) v[e] = f2bf(bf2f(v[e]) * QSCALE);
      qfrag[set][ks] = v;
    }
  }

  bf16x8 ones;
#pragma unroll
  for (int e = 0; e < 8; ++e) ones[e] = (short)0x3F80;   // bf16 1.0

  f32x4 lacc[2] = {f32x4(0.0f), f32x4(0.0f)};
  f32x4 oacc[2][8];
#pragma unroll
  for (int set = 0; set < 2; ++set)
#pragma unroll
    for (int j = 0; j < 8; ++j) oacc[set][j] = 0.0f;

  for (int st = 0; st < T_SEQ / 64; ++st) {
    const int s0 = st * 64;
    __syncthreads();   // all prior LDS reads (incl. Q frags at st=0) drained
    const short* kb = kbase + (long)s0 * NQKV;
#pragma unroll
    for (int t = 0; t < 4; ++t) {
      int chunk = w * 256 + t * 64 + lane;
      int r = chunk >> 4, c = chunk & 15;
      int gc = c ^ (r & 15);
      gload16(kb + (long)r * NQKV + gc * 8, Ks + (w * 256 + t * 64) * 8);
    }
    const short* vb = vbase + s0;
#pragma unroll
    for (int t = 0; t < 4; ++t) {
      int chunk = w * 256 + t * 64 + lane;
      int r = chunk >> 3, c = chunk & 7;
      int gc = c ^ (r & 7);
      gload16(vb + (long)r * T_SEQ + gc * 8, Vs + (w * 256 + t * 64) * 8);
    }
    __syncthreads();   // K,V resident

    // S = Q @ K^T per set (sequential sets keep sacc at 4 f32x4)
#pragma unroll
    for (int set = 0; set < 2; ++set) {
      f32x4 sacc[4];
#pragma unroll
      for (int j = 0; j < 4; ++j) sacc[j] = 0.0f;
#pragma unroll
      for (int ks = 0; ks < 4; ++ks) {
#pragma unroll
        for (int j = 0; j < 4; ++j) {
          int krow = j * 16 + l15;
          bf16x8 bfr = *(const bf16x8*)(Ks + krow * 128 + (((ks * 4 + quad) ^ (krow & 15)) * 8));
          sacc[j] = __builtin_amdgcn_mfma_f32_16x16x32_bf16(qfrag[set][ks], bfr, sacc[j], 0, 0, 0);
        }
      }
      // P = 2^(S'); same-wave Ps rows -> no barrier before PV
#pragma unroll
      for (int j = 0; j < 4; ++j)
#pragma unroll
        for (int r = 0; r < 4; ++r) {
          short pb = f2bf(fast_exp2(sacc[j][r]));
          int row = w * 32 + set * 16 + quad * 4 + r;
          int col = j * 16 + l15;
          Ps[row * 64 + (((col >> 3) ^ (row & 7)) * 8) + (col & 7)] = pb;
        }
    }

    // O += P @ V ; l += P @ 1 ; V-fragment reads shared across both sets
    const int qr0 = w * 32 + l15, qr1 = w * 32 + 16 + l15;
#pragma unroll
    for (int ks = 0; ks < 2; ++ks) {
      bf16x8 af0 = *(const bf16x8*)(Ps + qr0 * 64 + (((ks * 4 + quad) ^ (qr0 & 7)) * 8));
      bf16x8 af1 = *(const bf16x8*)(Ps + qr1 * 64 + (((ks * 4 + quad) ^ (qr1 & 7)) * 8));
      lacc[0] = __builtin_amdgcn_mfma_f32_16x16x32_bf16(af0, ones, lacc[0], 0, 0, 0);
      lacc[1] = __builtin_amdgcn_mfma_f32_16x16x32_bf16(af1, ones, lacc[1], 0, 0, 0);
#pragma unroll
      for (int j = 0; j < 8; ++j) {
        int vrow = j * 16 + l15;
        bf16x8 bfr = *(const bf16x8*)(Vs + vrow * 64 + (((ks * 4 + quad) ^ (vrow & 7)) * 8));
        oacc[0][j] = __builtin_amdgcn_mfma_f32_16x16x32_bf16(af0, bfr, oacc[0][j], 0, 0, 0);
        oacc[1][j] = __builtin_amdgcn_mfma_f32_16x16x32_bf16(af1, bfr, oacc[1][j], 0, 0, 0);
      }
    }
  }

  short* obase = aout + (long)(b * T_SEQ + qt * 128) * D_MODEL + h * HD;
#pragma unroll
  for (int set = 0; set < 2; ++set) {
    float inv[4];
#pragma unroll
    for (int r = 0; r < 4; ++r) inv[r] = 1.0f / lacc[set][r];
#pragma unroll
    for (int j = 0; j < 8; ++j)
#pragma unroll
      for (int r = 0; r < 4; ++r) {
        int row = w * 32 + set * 16 + quad * 4 + r;
        int col = j * 16 + l15;
        obase[(long)row * D_MODEL + col] = f2bf(oacc[set][j][r] * inv[r]);
      }
  }
}

// ---------------- launcher ----------------
extern "C" void kernel_launch(void* const* d_in, const int* in_sizes, int n_in,
                              void* d_out, int out_size, void* d_ws, size_t ws_size,
                              hipStream_t stream) {
  const float* x  = (const float*)d_in[0];
  const float* Wq = (const float*)d_in[1];
  const float* bq = (const float*)d_in[2];
  const float* Wk = (const float*)d_in[3];
  const float* bk = (const float*)d_in[4];
  const float* Wv = (const float*)d_in[5];
  const float* bv = (const float*)d_in[6];
  const float* Wo = (const float*)d_in[7];
  const float* bo = (const float*)d_in[8];

  const long NTOK = (long)NBATCH * T_SEQ;          // 4096
  short* xb    = (short*)d_ws;                     // [4096][2048]
  short* wqkvT = xb + NTOK * D_MODEL;              // [3072][2048]
  short* woT   = wqkvT + (long)NQKV * D_MODEL;     // [2048][2048]
  short* qkvb  = woT + (long)D_MODEL * D_MODEL;    // [4096][3072]
  short* vtb   = qkvb + NTOK * NQKV;               // [2][4][128][2048]
  short* attnb = vtb + (long)NBATCH * NG * HD * T_SEQ;  // [4096][2048]

  int nX = (int)(NTOK * D_MODEL);
  convert_x_kernel<<<nX / (256 * 4), 256, 0, stream>>>(x, xb, nX);
  wtrans_kernel<<<dim3(D_MODEL / 32, D_MODEL / 32), 256, 0, stream>>>(Wq, wqkvT, D_MODEL, D_MODEL, 0, D_MODEL);
  wtrans_kernel<<<dim3(D_MODEL / 32, 512 / 32), 256, 0, stream>>>(Wk, wqkvT, D_MODEL, 512, 2048, D_MODEL);
  wtrans_kernel<<<dim3(D_MODEL / 32, 512 / 32), 256, 0, stream>>>(Wv, wqkvT, D_MODEL, 512, 2560, D_MODEL);
  wtrans_kernel<<<dim3(D_MODEL / 32, D_MODEL / 32), 256, 0, stream>>>(Wo, woT, D_MODEL, D_MODEL, 0, D_MODEL);

  gemm_kernel<<<dim3(NQKV / 128, NTOK / 128), 256, 0, stream>>>(
      xb, wqkvT, bq, bk, bv, (void*)qkvb, (int)NTOK, NQKV, D_MODEL, 0);

  vtrans_kernel<<<dim3(T_SEQ / 32, HD / 32, NBATCH * NG), 256, 0, stream>>>(qkvb, vtb);

  attn_kernel<<<dim3(T_SEQ / 128, NH, NBATCH), 256, 0, stream>>>(qkvb, vtb, attnb);

  gemm_kernel<<<dim3(D_MODEL / 128, NTOK / 128), 256, 0, stream>>>(
      attnb, woT, bo, bo, bo, (void*)d_out, (int)NTOK, D_MODEL, D_MODEL, 1);
}

// Round 5
// 348.112 us; speedup vs baseline: 1.2024x; 1.2024x over previous
//
#include <hip/hip_runtime.h>

#define D_MODEL 2048
#define T_SEQ   2048
#define NBATCH  2
#define NH      16
#define NG      4
#define HD      128
#define NQKV    3072   // 2048 Q + 512 K + 512 V

typedef short bf16x8 __attribute__((ext_vector_type(8)));
typedef float f32x4  __attribute__((ext_vector_type(4)));
typedef short s16x4  __attribute__((ext_vector_type(4)));

__device__ __forceinline__ short f2bf(float f) {
  union { float f; unsigned u; } v; v.f = f;
  unsigned r = v.u + 0x7fffu + ((v.u >> 16) & 1u);   // RNE
  return (short)(r >> 16);
}

__device__ __forceinline__ float bf2f(short s) {
  union { unsigned u; float f; } v; v.u = ((unsigned)(unsigned short)s) << 16;
  return v.f;
}

__device__ __forceinline__ float fast_exp2(float x) {
#if __has_builtin(__builtin_amdgcn_exp2f)
  return __builtin_amdgcn_exp2f(x);
#else
  return __expf(x * 0.6931471805599453f);
#endif
}

__device__ __forceinline__ void gload16(const void* g, void* l) {
  __builtin_amdgcn_global_load_lds(
      (const __attribute__((address_space(1))) void*)g,
      (__attribute__((address_space(3))) void*)l, 16, 0, 0);
}

// ---------------- convert x (fp32 -> bf16) ----------------
__global__ __launch_bounds__(256) void convert_x_kernel(
    const float* __restrict__ x, short* __restrict__ o, int n) {
  int i = (blockIdx.x * 256 + threadIdx.x) * 4;
  if (i >= n) return;
  float4 v = *(const float4*)(x + i);
  s16x4 s;
  s[0] = f2bf(v.x); s[1] = f2bf(v.y); s[2] = f2bf(v.z); s[3] = f2bf(v.w);
  *(s16x4*)(o + i) = s;
}

// ------------- transpose+convert weights: dst[n][k] = W[k][n] -------------
__global__ __launch_bounds__(256) void wtrans_kernel(
    const float* __restrict__ W, short* __restrict__ dst,
    int K, int N, int rowOff, int dstStride) {
  __shared__ float t[32][33];
  int tx = threadIdx.x & 31, ty = threadIdx.x >> 5;   // ty 0..7
  int kb = blockIdx.x * 32, nb = blockIdx.y * 32;
#pragma unroll
  for (int i = 0; i < 4; ++i)
    t[ty + 8*i][tx] = W[(long)(kb + ty + 8*i) * N + nb + tx];
  __syncthreads();
#pragma unroll
  for (int i = 0; i < 4; ++i)
    dst[(long)(rowOff + nb + ty + 8*i) * dstStride + kb + tx] = f2bf(t[tx][ty + 8*i]);
}

// ------------- transpose V slice of QKV -> VT[b][g][d][s] (bf16) -------------
__global__ __launch_bounds__(256) void vtrans_kernel(
    const short* __restrict__ qkv, short* __restrict__ vt) {
  __shared__ short t[32][33];
  int bg = blockIdx.z; int b = bg >> 2, g = bg & 3;
  int sb = blockIdx.x * 32, db = blockIdx.y * 32;
  int tx = threadIdx.x & 31, ty = threadIdx.x >> 5;
  const short* src = qkv + (long)(b * T_SEQ) * NQKV + D_MODEL + NG * HD + g * HD;
#pragma unroll
  for (int i = 0; i < 4; ++i)
    t[ty + 8*i][tx] = src[(long)(sb + ty + 8*i) * NQKV + db + tx];
  __syncthreads();
  short* dst = vt + ((long)bg * HD + db) * T_SEQ + sb;
#pragma unroll
  for (int i = 0; i < 4; ++i)
    dst[(long)(ty + 8*i) * T_SEQ + tx] = t[tx][ty + 8*i];
}

// ---------------- bf16 MFMA GEMM: C[M][N] = A[M][K] @ BT[N][K]^T + bias ----------------
__global__ __launch_bounds__(256) void gemm_kernel(
    const short* __restrict__ A, const short* __restrict__ BT,
    const float* __restrict__ b0, const float* __restrict__ b1, const float* __restrict__ b2,
    void* __restrict__ Cout, int M, int N, int K, int mode) {
  __shared__ __align__(16) short As[128 * 32];
  __shared__ __align__(16) short Bs[128 * 32];
  const int tid = threadIdx.x;
  const int w = tid >> 6, lane = tid & 63;
  const int l15 = lane & 15, quad = lane >> 4;
  const int wr = w & 1, wc = w >> 1;
  const int nb = blockIdx.x, mb = blockIdx.y;
  const short* Ab = A + (long)mb * 128 * K;
  const short* Bb = BT + (long)nb * 128 * K;

  f32x4 acc[4][4];
#pragma unroll
  for (int i = 0; i < 4; ++i)
#pragma unroll
    for (int j = 0; j < 4; ++j) acc[i][j] = 0.0f;

  for (int k0 = 0; k0 < K; k0 += 32) {
    __syncthreads();
#pragma unroll
    for (int t = 0; t < 2; ++t) {
      int chunk = w * 128 + t * 64 + lane;
      int r = chunk >> 2, c = chunk & 3;
      int gc = c ^ ((r >> 1) & 3);              // XOR swizzle (16B chunks)
      gload16(Ab + (long)r * K + k0 + gc * 8, As + (w * 128 + t * 64) * 8);
      gload16(Bb + (long)r * K + k0 + gc * 8, Bs + (w * 128 + t * 64) * 8);
    }
    __syncthreads();
    bf16x8 af[4], bfr[4];
#pragma unroll
    for (int i = 0; i < 4; ++i) {
      int r = wr * 64 + i * 16 + l15;
      af[i] = *(const bf16x8*)(As + r * 32 + ((quad ^ ((r >> 1) & 3)) * 8));
    }
#pragma unroll
    for (int j = 0; j < 4; ++j) {
      int r = wc * 64 + j * 16 + l15;
      bfr[j] = *(const bf16x8*)(Bs + r * 32 + ((quad ^ ((r >> 1) & 3)) * 8));
    }
#pragma unroll
    for (int i = 0; i < 4; ++i)
#pragma unroll
      for (int j = 0; j < 4; ++j)
        acc[i][j] = __builtin_amdgcn_mfma_f32_16x16x32_bf16(af[i], bfr[j], acc[i][j], 0, 0, 0);
  }

  float biasv[4];
#pragma unroll
  for (int j = 0; j < 4; ++j) {
    int col = nb * 128 + wc * 64 + j * 16 + l15;
    float bv;
    if (mode == 0) {
      if (col < 2048)      bv = b0[col];
      else if (col < 2560) bv = b1[col - 2048];
      else                 bv = b2[col - 2560];
    } else bv = b0[col];
    biasv[j] = bv;
  }
  if (mode == 0) {
    short* C = (short*)Cout;
#pragma unroll
    for (int i = 0; i < 4; ++i)
#pragma unroll
      for (int j = 0; j < 4; ++j)
#pragma unroll
        for (int r = 0; r < 4; ++r) {
          int row = mb * 128 + wr * 64 + i * 16 + quad * 4 + r;
          int col = nb * 128 + wc * 64 + j * 16 + l15;
          C[(long)row * N + col] = f2bf(acc[i][j][r] + biasv[j]);
        }
  } else {
    float* C = (float*)Cout;
#pragma unroll
    for (int i = 0; i < 4; ++i)
#pragma unroll
      for (int j = 0; j < 4; ++j)
#pragma unroll
        for (int r = 0; r < 4; ++r) {
          int row = mb * 128 + wr * 64 + i * 16 + quad * 4 + r;
          int col = nb * 128 + wc * 64 + j * 16 + l15;
          C[(long)row * N + col] = acc[i][j][r] + biasv[j];
        }
  }
}

// ---------------- fused attention v5: v2 tiles, 2-wave blocks, explicit reuse ----
// grid: (T/64, NH, B) = 1024 blocks; block 128 threads (2 waves). 64 Q rows
// per block; wave w owns rows [w*32, w*32+32) as TWO 16-row register A-sets.
// All LDS fragment reads explicitly interleaved so one ds_read_b128 feeds
// TWO MFMAs (sets share K and V fragments in straight-line code — no
// compiler CSE needed). Per wave-iter: 16 K + 4 P + 16 V = 36 b128 reads for
// 68 MFMAs (v2: 34/34). LDS 40 KB -> 4 blocks/CU (8 waves). Same swizzles
// as v2 (0 bank conflicts). 2 barriers per s-tile.
__global__ __launch_bounds__(128, 2) void attn_kernel(
    const short* __restrict__ qkv, const short* __restrict__ vt,
    short* __restrict__ aout) {
  __shared__ __align__(16) short smem[20480];   // 40 KB
  short* Ks = smem;              // 64 rows(s) x 128 (k); also Q staging
  short* Vs = smem + 8192;       // 128 rows(d) x 64 (s)
  short* Ps = smem + 16384;      // 64 rows(q) x 64 (s)

  const int tid = threadIdx.x;
  const int w = tid >> 6, lane = tid & 63;   // w in {0,1}
  const int l15 = lane & 15, quad = lane >> 4;
  const int qt = blockIdx.x, h = blockIdx.y, b = blockIdx.z;
  const int g = h >> 2;
  const short* qbase = qkv + (long)(b * T_SEQ + qt * 64) * NQKV + h * HD;
  const short* kbase = qkv + (long)(b * T_SEQ) * NQKV + D_MODEL + g * HD;
  const short* vbase = vt + (long)(b * NG + g) * HD * T_SEQ;
  const float QSCALE = 0.08838834764831845f * 1.4426950408889634f;  // 1/sqrt(128)*log2(e)

  // ---- stage Q tile (64x128) through Ks, pull both A-sets to registers ----
#pragma unroll
  for (int t = 0; t < 8; ++t) {
    int chunk = w * 512 + t * 64 + lane;        // 0..1023
    int r = chunk >> 4, c = chunk & 15;
    int gc = c ^ (r & 15);
    gload16(qbase + (long)r * NQKV + gc * 8, Ks + (w * 512 + t * 64) * 8);
  }
  __syncthreads();
  bf16x8 qfrag[2][4];
#pragma unroll
  for (int set = 0; set < 2; ++set) {
    int qr = w * 32 + set * 16 + l15;
#pragma unroll
    for (int ks = 0; ks < 4; ++ks) {
      bf16x8 v = *(const bf16x8*)(Ks + qr * 128 + (((ks * 4 + quad) ^ (qr & 15)) * 8));
#pragma unroll
      for (int e = 0; e < 8; ++e) v[e] = f2bf(bf2f(v[e]) * QSCALE);
      qfrag[set][ks] = v;
    }
  }

  bf16x8 ones;
#pragma unroll
  for (int e = 0; e < 8; ++e) ones[e] = (short)0x3F80;   // bf16 1.0

  f32x4 lacc[2] = {f32x4(0.0f), f32x4(0.0f)};
  f32x4 oacc[2][8];
#pragma unroll
  for (int set = 0; set < 2; ++set)
#pragma unroll
    for (int j = 0; j < 8; ++j) oacc[set][j] = 0.0f;

  for (int st = 0; st < T_SEQ / 64; ++st) {
    const int s0 = st * 64;
    __syncthreads();   // all prior LDS reads (incl. Q frags at st=0) drained
    const short* kb = kbase + (long)s0 * NQKV;
#pragma unroll
    for (int t = 0; t < 8; ++t) {
      int chunk = w * 512 + t * 64 + lane;
      int r = chunk >> 4, c = chunk & 15;
      int gc = c ^ (r & 15);
      gload16(kb + (long)r * NQKV + gc * 8, Ks + (w * 512 + t * 64) * 8);
    }
    const short* vb = vbase + s0;
#pragma unroll
    for (int t = 0; t < 8; ++t) {
      int chunk = w * 512 + t * 64 + lane;
      int r = chunk >> 3, c = chunk & 7;
      int gc = c ^ (r & 7);
      gload16(vb + (long)r * T_SEQ + gc * 8, Vs + (w * 512 + t * 64) * 8);
    }
    __syncthreads();   // K,V resident

    // S = Q @ K^T, both sets per K-fragment read (explicit 1 read : 2 MFMA)
    f32x4 sacc[2][4];
#pragma unroll
    for (int set = 0; set < 2; ++set)
#pragma unroll
      for (int j = 0; j < 4; ++j) sacc[set][j] = 0.0f;
#pragma unroll
    for (int ks = 0; ks < 4; ++ks) {
#pragma unroll
      for (int j = 0; j < 4; ++j) {
        int krow = j * 16 + l15;
        bf16x8 bfr = *(const bf16x8*)(Ks + krow * 128 + (((ks * 4 + quad) ^ (krow & 15)) * 8));
        sacc[0][j] = __builtin_amdgcn_mfma_f32_16x16x32_bf16(qfrag[0][ks], bfr, sacc[0][j], 0, 0, 0);
        sacc[1][j] = __builtin_amdgcn_mfma_f32_16x16x32_bf16(qfrag[1][ks], bfr, sacc[1][j], 0, 0, 0);
      }
    }

    // P = 2^(S'); same-wave Ps rows -> no barrier before PV
#pragma unroll
    for (int set = 0; set < 2; ++set)
#pragma unroll
      for (int j = 0; j < 4; ++j)
#pragma unroll
        for (int r = 0; r < 4; ++r) {
          short pb = f2bf(fast_exp2(sacc[set][j][r]));
          int row = w * 32 + set * 16 + quad * 4 + r;
          int col = j * 16 + l15;
          Ps[row * 64 + (((col >> 3) ^ (row & 7)) * 8) + (col & 7)] = pb;
        }

    // O += P @ V ; l += P @ 1 ; one V-fragment read feeds both sets
    const int qr0 = w * 32 + l15, qr1 = qr0 + 16;
#pragma unroll
    for (int ks = 0; ks < 2; ++ks) {
      bf16x8 af0 = *(const bf16x8*)(Ps + qr0 * 64 + (((ks * 4 + quad) ^ (qr0 & 7)) * 8));
      bf16x8 af1 = *(const bf16x8*)(Ps + qr1 * 64 + (((ks * 4 + quad) ^ (qr1 & 7)) * 8));
      lacc[0] = __builtin_amdgcn_mfma_f32_16x16x32_bf16(af0, ones, lacc[0], 0, 0, 0);
      lacc[1] = __builtin_amdgcn_mfma_f32_16x16x32_bf16(af1, ones, lacc[1], 0, 0, 0);
#pragma unroll
      for (int j = 0; j < 8; ++j) {
        int vrow = j * 16 + l15;
        bf16x8 bfr = *(const bf16x8*)(Vs + vrow * 64 + (((ks * 4 + quad) ^ (vrow & 7)) * 8));
        oacc[0][j] = __builtin_amdgcn_mfma_f32_16x16x32_bf16(af0, bfr, oacc[0][j], 0, 0, 0);
        oacc[1][j] = __builtin_amdgcn_mfma_f32_16x16x32_bf16(af1, bfr, oacc[1][j], 0, 0, 0);
      }
    }
  }

  short* obase = aout + (long)(b * T_SEQ + qt * 64) * D_MODEL + h * HD;
#pragma unroll
  for (int set = 0; set < 2; ++set) {
    float inv[4];
#pragma unroll
    for (int r = 0; r < 4; ++r) inv[r] = 1.0f / lacc[set][r];
#pragma unroll
    for (int j = 0; j < 8; ++j)
#pragma unroll
      for (int r = 0; r < 4; ++r) {
        int row = w * 32 + set * 16 + quad * 4 + r;
        int col = j * 16 + l15;
        obase[(long)row * D_MODEL + col] = f2bf(oacc[set][j][r] * inv[r]);
      }
  }
}

// ---------------- launcher ----------------
extern "C" void kernel_launch(void* const* d_in, const int* in_sizes, int n_in,
                              void* d_out, int out_size, void* d_ws, size_t ws_size,
                              hipStream_t stream) {
  const float* x  = (const float*)d_in[0];
  const float* Wq = (const float*)d_in[1];
  const float* bq = (const float*)d_in[2];
  const float* Wk = (const float*)d_in[3];
  const float* bk = (const float*)d_in[4];
  const float* Wv = (const float*)d_in[5];
  const float* bv = (const float*)d_in[6];
  const float* Wo = (const float*)d_in[7];
  const float* bo = (const float*)d_in[8];

  const long NTOK = (long)NBATCH * T_SEQ;          // 4096
  short* xb    = (short*)d_ws;                     // [4096][2048]
  short* wqkvT = xb + NTOK * D_MODEL;              // [3072][2048]
  short* woT   = wqkvT + (long)NQKV * D_MODEL;     // [2048][2048]
  short* qkvb  = woT + (long)D_MODEL * D_MODEL;    // [4096][3072]
  short* vtb   = qkvb + NTOK * NQKV;               // [2][4][128][2048]
  short* attnb = vtb + (long)NBATCH * NG * HD * T_SEQ;  // [4096][2048]

  int nX = (int)(NTOK * D_MODEL);
  convert_x_kernel<<<nX / (256 * 4), 256, 0, stream>>>(x, xb, nX);
  wtrans_kernel<<<dim3(D_MODEL / 32, D_MODEL / 32), 256, 0, stream>>>(Wq, wqkvT, D_MODEL, D_MODEL, 0, D_MODEL);
  wtrans_kernel<<<dim3(D_MODEL / 32, 512 / 32), 256, 0, stream>>>(Wk, wqkvT, D_MODEL, 512, 2048, D_MODEL);
  wtrans_kernel<<<dim3(D_MODEL / 32, 512 / 32), 256, 0, stream>>>(Wv, wqkvT, D_MODEL, 512, 2560, D_MODEL);
  wtrans_kernel<<<dim3(D_MODEL / 32, D_MODEL / 32), 256, 0, stream>>>(Wo, woT, D_MODEL, D_MODEL, 0, D_MODEL);

  gemm_kernel<<<dim3(NQKV / 128, NTOK / 128), 256, 0, stream>>>(
      xb, wqkvT, bq, bk, bv, (void*)qkvb, (int)NTOK, NQKV, D_MODEL, 0);

  vtrans_kernel<<<dim3(T_SEQ / 32, HD / 32, NBATCH * NG), 256, 0, stream>>>(qkvb, vtb);

  attn_kernel<<<dim3(T_SEQ / 64, NH, NBATCH), 128, 0, stream>>>(qkvb, vtb, attnb);

  gemm_kernel<<<dim3(D_MODEL / 128, NTOK / 128), 256, 0, stream>>>(
      attnb, woT, bo, bo, bo, (void*)d_out, (int)NTOK, D_MODEL, D_MODEL, 1);
}